// Round 8
// baseline (433.922 us; speedup 1.0000x reference)
//
#include <hip/hip_runtime.h>

#define NN   8192
#define FIN  128
#define HH   256
#define CAP  128   // max neighbors kept per row; E[deg]~32, max ~70, P(>128) ~ 0

typedef float    f32x4 __attribute__((ext_vector_type(4)));
typedef float    f32x2 __attribute__((ext_vector_type(2)));
typedef _Float16 f16x8 __attribute__((ext_vector_type(8)));
typedef _Float16 f16x4 __attribute__((ext_vector_type(4)));
typedef _Float16 f16x2 __attribute__((ext_vector_type(2)));

__device__ __forceinline__ const f32x4* c4(const float* p) { return (const f32x4*)p; }
__device__ __forceinline__       f32x4* p4(float* p)       { return (f32x4*)p; }
__device__ __forceinline__ const f32x2* c2(const float* p) { return (const f32x2*)p; }
__device__ __forceinline__       f32x2* p2(float* p)       { return (f32x2*)p; }

// ---------------------------------------------------------------------------
// Blocks 0..NN-1: scan one row of A (nontemporal stream) -> adjacency list,
// dinv = 1/sqrt(deg+1), expo = t*deg/(deg+1e-8).
// Tail blocks (hidden under the BW-bound scan):
//   NN..NN+127 : X -> fp16
//   NN+128..131: W2^T -> fp16   (BT[n][k], for MFMA B-frags)
//   NN+132..135: W_emb^T -> fp16 (rows 0..255 only; exposure row stays fp32)
// ---------------------------------------------------------------------------
__global__ __launch_bounds__(256) void k_build(
    const float* __restrict__ A, const float* __restrict__ treat,
    const float* __restrict__ X,
    const float* __restrict__ W2, const float* __restrict__ W_emb,
    int* __restrict__ cols, int* __restrict__ cnt,
    float* __restrict__ dinv, float* __restrict__ expo,
    _Float16* __restrict__ Xh, _Float16* __restrict__ W2T,
    _Float16* __restrict__ WembT)
{
  const int row = blockIdx.x;
  if (row >= NN) {
    const int q = row - NN;
    if (q < 128) {                       // X -> fp16
      const int t0 = q * 256 + threadIdx.x;
      for (int i = t0; i < NN * FIN / 4; i += 128 * 256) {
        const f32x4 v = *c4(&X[(size_t)i * 4]);
        f16x4 h = {(_Float16)v[0], (_Float16)v[1], (_Float16)v[2], (_Float16)v[3]};
        *(f16x4*)&Xh[(size_t)i * 4] = h;
      }
    } else if (q < 132) {                // W2 transpose -> fp16
      for (int e = (q - 128) * 256 + threadIdx.x; e < HH * HH; e += 1024) {
        const int k = e >> 8, n = e & 255;
        W2T[(size_t)n * HH + k] = (_Float16)W2[e];
      }
    } else {                             // W_emb (rows 0..255) transpose -> fp16
      for (int e = (q - 132) * 256 + threadIdx.x; e < HH * HH; e += 1024) {
        const int k = e >> 8, n = e & 255;
        WembT[(size_t)n * HH + k] = (_Float16)W_emb[e];
      }
    }
    return;
  }

  const f32x4* Ar = c4(A + (size_t)row * NN);
  __shared__ int   s_cnt;
  __shared__ float s_rs[4];
  if (threadIdx.x == 0) s_cnt = 0;
  __syncthreads();

  float rs = 0.f;
  int* myCols = cols + (size_t)row * CAP;
  #pragma unroll
  for (int it = 0; it < NN / 4 / 256; ++it) {
    const int idx = it * 256 + threadIdx.x;
    const f32x4 a = __builtin_nontemporal_load(Ar + idx);
    const int base = idx * 4;
    #pragma unroll
    for (int u = 0; u < 4; ++u) {
      if (a[u] != 0.0f) {
        rs += a[u];
        int p = atomicAdd(&s_cnt, 1);
        if (p < CAP) myCols[p] = base + u;
      }
    }
  }
  #pragma unroll
  for (int off = 32; off > 0; off >>= 1) rs += __shfl_down(rs, off);
  const int wid = threadIdx.x >> 6;
  if ((threadIdx.x & 63) == 0) s_rs[wid] = rs;
  __syncthreads();
  if (threadIdx.x == 0) {
    const float R = s_rs[0] + s_rs[1] + s_rs[2] + s_rs[3];
    int n = s_cnt; if (n > CAP) n = CAP;
    cnt[row]  = n;
    dinv[row] = rsqrtf(R + 1.0f);
    expo[row] = treat[row] * R / (R + 1e-8f);
  }
}

// ---------------------------------------------------------------------------
// agg0: out[i,:] = dinv[i]*(sum_j dinv[j]*Xh[j,:] + dinv[i]*Xh[i,:])
// fp16 gather, fp32 accumulate, fp32 out (feeds the VALU gemm1).
// ---------------------------------------------------------------------------
__global__ __launch_bounds__(256) void k_agg0h(
    const _Float16* __restrict__ Xh,
    const int* __restrict__ cols, const int* __restrict__ cnt,
    const float* __restrict__ dinv, float* __restrict__ out)
{
  const int wid  = threadIdx.x >> 6;
  const int lane = threadIdx.x & 63;
  const int i    = blockIdx.x * 4 + wid;
  __shared__ int   s_cols[4][CAP];
  __shared__ float s_w[4][CAP];

  const int n = cnt[i];
  if (lane < n) {
    const int j = cols[(size_t)i * CAP + lane];
    s_cols[wid][lane] = j;  s_w[wid][lane] = dinv[j];
  }
  if (lane + 64 < n) {
    const int j = cols[(size_t)i * CAP + lane + 64];
    s_cols[wid][lane + 64] = j;  s_w[wid][lane + 64] = dinv[j];
  }
  __syncthreads();

  const float di = dinv[i];
  const f16x2 sv = *(const f16x2*)&Xh[(size_t)i * FIN + 2 * lane];
  f32x2 acc = {di * (float)sv[0], di * (float)sv[1]};
  #pragma unroll 4
  for (int t = 0; t < n; ++t) {
    const int   j = s_cols[wid][t];
    const float w = s_w[wid][t];
    const f16x2 v = *(const f16x2*)&Xh[(size_t)j * FIN + 2 * lane];
    acc[0] += w * (float)v[0];
    acc[1] += w * (float)v[1];
  }
  *p2(&out[(size_t)i * FIN + 2 * lane]) = di * acc;
}

// ---------------------------------------------------------------------------
// agg on 256-wide fp16 M -> fp16 out (feeds the MFMA gemm3):
// out[i,:] = (f16) relu(dinv[i]*(sum dinv[j]*M[j,:] + dinv[i]*M[i,:]) + b)
// fp32 accumulate.  INIT: first blocks write head biases into y0/y1.
// ---------------------------------------------------------------------------
template<bool INIT>
__global__ __launch_bounds__(256) void k_aggh(
    const _Float16* __restrict__ M,
    const int* __restrict__ cols, const int* __restrict__ cnt,
    const float* __restrict__ dinv, const float* __restrict__ bias,
    _Float16* __restrict__ out,
    float* __restrict__ dout, const float* __restrict__ bt0, const float* __restrict__ bt1)
{
  const int wid  = threadIdx.x >> 6;
  const int lane = threadIdx.x & 63;
  const int i    = blockIdx.x * 4 + wid;
  __shared__ int   s_cols[4][CAP];
  __shared__ float s_w[4][CAP];

  if constexpr (INIT) {
    if (blockIdx.x < 64) {
      const int idx = blockIdx.x * 256 + threadIdx.x;   // 16384 = y0,y1
      dout[idx] = (idx < NN) ? bt0[0] : bt1[0];
    }
  }

  const int n = cnt[i];
  if (lane < n) {
    const int j = cols[(size_t)i * CAP + lane];
    s_cols[wid][lane] = j;  s_w[wid][lane] = dinv[j];
  }
  if (lane + 64 < n) {
    const int j = cols[(size_t)i * CAP + lane + 64];
    s_cols[wid][lane + 64] = j;  s_w[wid][lane + 64] = dinv[j];
  }
  __syncthreads();

  const float di = dinv[i];
  const f32x4 bias4 = *c4(&bias[lane * 4]);
  const f16x4 sv = *(const f16x4*)&M[(size_t)i * HH + 4 * lane];
  f32x4 acc = {di * (float)sv[0], di * (float)sv[1],
               di * (float)sv[2], di * (float)sv[3]};
  #pragma unroll 4
  for (int t = 0; t < n; ++t) {
    const int   j = s_cols[wid][t];
    const float w = s_w[wid][t];
    const f16x4 v = *(const f16x4*)&M[(size_t)j * HH + 4 * lane];
    acc[0] += w * (float)v[0];
    acc[1] += w * (float)v[1];
    acc[2] += w * (float)v[2];
    acc[3] += w * (float)v[3];
  }
  f32x4 o = di * acc + bias4;
  f16x4 oh;
  #pragma unroll
  for (int q = 0; q < 4; ++q) oh[q] = (_Float16)fmaxf(o[q], 0.f);
  *(f16x4*)&out[(size_t)i * HH + 4 * lane] = oh;
}

// ---------------------------------------------------------------------------
// MFMA fp16 GEMM: out[8192 x 256] = Ah[8192 x 256] @ B, B given TRANSPOSED
// fp16 (BT[n][k]).  Block = 4 waves, 64 rows x 64 cols; wave = 16 rows.
// Per wave K-step: 1 A-frag + 4 B-frag contiguous f16x8 loads + 4 MFMA.
// Frag layout (HW-verified m89): A row=lane&15, k=(lane>>4)*8+i;
// B col=lane&15, same k; D col=lane&15, row=(lane>>4)*4+reg.
// FIN_EPI=false: raw fp16 out (gemm2).  FIN_EPI=true: +expo*ebrow +bias,
// relu, fp32 out, fused y0/y1 head dots (quarter-wave shfl + atomics).
// ---------------------------------------------------------------------------
template<bool FIN_EPI>
__global__ __launch_bounds__(256) void k_gemm_mfma(
    const _Float16* __restrict__ Ah, const _Float16* __restrict__ BT,
    const float* __restrict__ Wfull,   // fp32 W_emb (exposure row) [FIN_EPI]
    const float* __restrict__ bias, const float* __restrict__ expo,
    const float* __restrict__ Wt0, const float* __restrict__ Wt1,
    float* __restrict__ out, _Float16* __restrict__ out16,
    float* __restrict__ y0, float* __restrict__ y1)
{
  const int tid = threadIdx.x;
  const int w = tid >> 6, l = tid & 63;
  const int r0 = (blockIdx.x & 127) * 64 + w * 16;   // wave's 16 rows
  const int c0 = (blockIdx.x >> 7) * 64;             // block's 64 cols
  const int lr = l & 15;                             // frag row/col index
  const int lk = (l >> 4) * 8;                       // frag k offset

  f32x4 acc[4] = {{0.f,0.f,0.f,0.f},{0.f,0.f,0.f,0.f},
                  {0.f,0.f,0.f,0.f},{0.f,0.f,0.f,0.f}};
  const _Float16* Aptr = Ah + (size_t)(r0 + lr) * HH + lk;
  const _Float16* Bptr = BT + (size_t)(c0 + lr) * HH + lk;

  #pragma unroll
  for (int k0 = 0; k0 < HH; k0 += 32) {
    const f16x8 a = *(const f16x8*)(Aptr + k0);
    #pragma unroll
    for (int nt = 0; nt < 4; ++nt) {
      const f16x8 b = *(const f16x8*)(Bptr + (size_t)nt * 16 * HH + k0);
      acc[nt] = __builtin_amdgcn_mfma_f32_16x16x32_f16(a, b, acc[nt], 0, 0, 0);
    }
  }

  const int rbase = r0 + (l >> 4) * 4;   // this quarter-wave's 4 output rows
  if constexpr (!FIN_EPI) {
    #pragma unroll
    for (int r = 0; r < 4; ++r)
      #pragma unroll
      for (int nt = 0; nt < 4; ++nt)
        out16[(size_t)(rbase + r) * HH + c0 + 16 * nt + lr] = (_Float16)acc[nt][r];
  } else {
    float eb[4], bs[4], w0[4], w1[4];
    #pragma unroll
    for (int nt = 0; nt < 4; ++nt) {
      const int c = c0 + 16 * nt + lr;
      eb[nt] = Wfull[(size_t)HH * HH + c];   // exposure row of W_emb (fp32)
      bs[nt] = bias[c];
      w0[nt] = Wt0[c];
      w1[nt] = Wt1[c];
    }
    #pragma unroll
    for (int r = 0; r < 4; ++r) {
      const int R = rbase + r;
      const float e = expo[R];
      float s0 = 0.f, s1 = 0.f;
      #pragma unroll
      for (int nt = 0; nt < 4; ++nt) {
        float v = fmaxf(acc[nt][r] + e * eb[nt] + bs[nt], 0.f);
        out[(size_t)R * HH + c0 + 16 * nt + lr] = v;
        s0 += v * w0[nt];
        s1 += v * w1[nt];
      }
      // reduce over the 16 lanes of this quarter-wave (offs 8,4,2,1:
      // junk from cross-group reads never reaches group-lane 0)
      #pragma unroll
      for (int off = 8; off > 0; off >>= 1) {
        s0 += __shfl_down(s0, off);
        s1 += __shfl_down(s1, off);
      }
      if (lr == 0) {
        atomicAdd(&y0[R], s0);
        atomicAdd(&y1[R], s1);
      }
    }
  }
}

// ---------------------------------------------------------------------------
// VALU fp32 GEMM (kept for gemm1, K=128): out fp16 = relu(M @ W + b)
// 64x64 tile, 4x4 micro-tile, KT=16 LDS panels with register prefetch.
// ---------------------------------------------------------------------------
template<int K>
__global__ __launch_bounds__(256) void k_gemm_v(
    const float* __restrict__ M, const float* __restrict__ W,
    const float* __restrict__ bias, _Float16* __restrict__ out16)
{
  __shared__ float As[16][64];
  __shared__ float Bs[16][64];
  const int tid = threadIdx.x;
  const int tx = tid & 15, ty = tid >> 4;
  const int bx = blockIdx.x & 127, by = blockIdx.x >> 7;
  const int r0 = bx * 64, c0 = by * 64;
  const int la_r = tid & 63;
  const int la_k = (tid >> 6) << 2;
  const int lb_k = tid >> 4;
  const int lb_c = (tid & 15) << 2;

  const float* Abase = M + (size_t)(r0 + la_r) * K + la_k;
  const float* Bbase = W + (size_t)lb_k * HH + c0 + lb_c;

  f32x4 aR = *c4(Abase);
  f32x4 bR = *c4(Bbase);
  float acc[4][4] = {};

  #pragma unroll 1
  for (int k0 = 0; k0 < K; k0 += 16) {
    As[la_k + 0][la_r] = aR[0];
    As[la_k + 1][la_r] = aR[1];
    As[la_k + 2][la_r] = aR[2];
    As[la_k + 3][la_r] = aR[3];
    *p4(&Bs[lb_k][lb_c]) = bR;
    __syncthreads();
    if (k0 + 16 < K) {
      aR = *c4(Abase + k0 + 16);
      bR = *c4(Bbase + (size_t)(k0 + 16) * HH);
    }
    #pragma unroll
    for (int kk = 0; kk < 16; ++kk) {
      const f32x4 av = *c4(&As[kk][ty * 4]);
      const f32x4 bv = *c4(&Bs[kk][tx * 4]);
      #pragma unroll
      for (int i = 0; i < 4; ++i)
        #pragma unroll
        for (int j = 0; j < 4; ++j)
          acc[i][j] += av[i] * bv[j];
    }
    __syncthreads();
  }

  const f32x4 bs = *c4(&bias[c0 + tx * 4]);
  #pragma unroll
  for (int i = 0; i < 4; ++i) {
    const int r = r0 + ty * 4 + i;
    f16x4 oh;
    #pragma unroll
    for (int j = 0; j < 4; ++j) oh[j] = (_Float16)fmaxf(acc[i][j] + bs[j], 0.f);
    *(f16x4*)&out16[(size_t)r * HH + c0 + tx * 4] = oh;
  }
}

// ---------------------------------------------------------------------------
extern "C" void kernel_launch(void* const* d_in, const int* in_sizes, int n_in,
                              void* d_out, int out_size, void* d_ws, size_t ws_size,
                              hipStream_t stream)
{
  const float* A      = (const float*)d_in[0];
  const float* feats  = (const float*)d_in[1];
  const float* treat  = (const float*)d_in[2];
  const float* W1     = (const float*)d_in[3];
  const float* b1     = (const float*)d_in[4];
  const float* W2     = (const float*)d_in[5];
  const float* b2     = (const float*)d_in[6];
  const float* W_emb  = (const float*)d_in[7];
  const float* b_emb  = (const float*)d_in[8];
  const float* W_t0   = (const float*)d_in[9];
  const float* b_t0   = (const float*)d_in[10];
  const float* W_t1   = (const float*)d_in[11];
  const float* b_t1   = (const float*)d_in[12];
  float* dout = (float*)d_out;

  // workspace layout (~22.5 MiB, all 16B-aligned)
  int*      cols  = (int*)d_ws;                      // NN*CAP ints (4 MiB)
  int*      cnt   = cols + (size_t)NN * CAP;         // NN
  float*    dinv  = (float*)(cnt + NN);              // NN
  float*    expo  = dinv + NN;                       // NN
  float*    bufX  = expo + NN;                       // NN*FIN f32 (4 MiB)
  _Float16* Xh    = (_Float16*)(bufX + (size_t)NN * FIN);  // NN*FIN f16 (2 MiB)
  _Float16* h1h   = Xh + (size_t)NN * FIN;           // NN*HH f16 (4 MiB)
  _Float16* h1w2h = h1h + (size_t)NN * HH;           // NN*HH f16 (4 MiB)
  _Float16* h2h   = h1w2h + (size_t)NN * HH;         // NN*HH f16 (4 MiB)
  _Float16* W2T   = h2h + (size_t)NN * HH;           // HH*HH f16 (128 KiB)
  _Float16* WembT = W2T + (size_t)HH * HH;           // HH*HH f16 (128 KiB)

  float* y0  = dout;
  float* y1  = dout + NN;
  float* emb = dout + 2 * NN;

  // 1. A scan + fp16 conversions (X, W2^T, W_emb^T) in tail blocks
  k_build<<<NN + 136, 256, 0, stream>>>(A, treat, feats, W2, W_emb,
                                        cols, cnt, dinv, expo, Xh, W2T, WembT);
  // 2. aggX = nA @ X   (fp16 gather, fp32 out)
  k_agg0h<<<NN / 4, 256, 0, stream>>>(Xh, cols, cnt, dinv, bufX);
  // 3. h1 = relu(aggX @ W1 + b1) -> fp16   (VALU fp32 GEMM)
  k_gemm_v<FIN><<<512, 256, 0, stream>>>(bufX, W1, b1, h1h);
  // 4. h1W2 = h1 @ W2 -> fp16              (MFMA fp16)
  k_gemm_mfma<false><<<512, 256, 0, stream>>>(
      h1h, W2T, nullptr, nullptr, nullptr, nullptr, nullptr,
      nullptr, h1w2h, nullptr, nullptr);
  // 5. h2 = relu(nA @ h1W2 + b2) -> fp16   (fp16 gather; + y0/y1 bias init)
  k_aggh<true><<<NN / 4, 256, 0, stream>>>(h1w2h, cols, cnt, dinv, b2, h2h,
                                           dout, b_t0, b_t1);
  // 6. emb = relu(h2 @ W_emb + expo*ebrow + b_emb) + heads  (MFMA fp16)
  k_gemm_mfma<true><<<512, 256, 0, stream>>>(
      h2h, WembT, W_emb, b_emb, expo, W_t0, W_t1,
      emb, nullptr, y0, y1);
}

// Round 9
// 432.593 us; speedup vs baseline: 1.0031x; 1.0031x over previous
//
#include <hip/hip_runtime.h>

#define NN   8192
#define FIN  128
#define HH   256
#define CAP  128   // max neighbors kept per row; E[deg]~32, max ~70, P(>128) ~ 0

typedef float    f32x4 __attribute__((ext_vector_type(4)));
typedef float    f32x2 __attribute__((ext_vector_type(2)));
typedef _Float16 f16x8 __attribute__((ext_vector_type(8)));
typedef _Float16 f16x4 __attribute__((ext_vector_type(4)));
typedef _Float16 f16x2 __attribute__((ext_vector_type(2)));

__device__ __forceinline__ const f32x4* c4(const float* p) { return (const f32x4*)p; }
__device__ __forceinline__       f32x4* p4(float* p)       { return (f32x4*)p; }

// ---------------------------------------------------------------------------
// Blocks 0..NN-1: scan one row of A (nontemporal stream) -> adjacency list,
// dinv = 1/sqrt(deg+1), expo = t*deg/(deg+1e-8).
// Tail blocks (hidden under the BW-bound scan):
//   q=row-NN in [0,128)  : X -> fp16
//   q in [128,132)       : W2^T  -> fp16  (BT[n][k])
//   q in [132,136)       : W_emb^T (rows 0..255) -> fp16
//   q in [136,138)       : W1^T  -> fp16
//   q in [138,146)       : y0/y1 head-bias init in d_out
// ---------------------------------------------------------------------------
__global__ __launch_bounds__(256) void k_build(
    const float* __restrict__ A, const float* __restrict__ treat,
    const float* __restrict__ X,
    const float* __restrict__ W1, const float* __restrict__ W2,
    const float* __restrict__ W_emb,
    const float* __restrict__ bt0, const float* __restrict__ bt1,
    int* __restrict__ cols, int* __restrict__ cnt,
    float* __restrict__ dinv, float* __restrict__ expo,
    _Float16* __restrict__ Xh, _Float16* __restrict__ W1T,
    _Float16* __restrict__ W2T, _Float16* __restrict__ WembT,
    float* __restrict__ dout)
{
  const int row = blockIdx.x;
  if (row >= NN) {
    const int q = row - NN;
    if (q < 128) {                       // X -> fp16
      const int t0 = q * 256 + threadIdx.x;
      for (int i = t0; i < NN * FIN / 4; i += 128 * 256) {
        const f32x4 v = *c4(&X[(size_t)i * 4]);
        f16x4 h = {(_Float16)v[0], (_Float16)v[1], (_Float16)v[2], (_Float16)v[3]};
        *(f16x4*)&Xh[(size_t)i * 4] = h;
      }
    } else if (q < 132) {                // W2^T
      for (int e = (q - 128) * 256 + threadIdx.x; e < HH * HH; e += 1024) {
        const int k = e >> 8, n = e & 255;
        W2T[(size_t)n * HH + k] = (_Float16)W2[e];
      }
    } else if (q < 136) {                // W_emb^T (first HH rows)
      for (int e = (q - 132) * 256 + threadIdx.x; e < HH * HH; e += 1024) {
        const int k = e >> 8, n = e & 255;
        WembT[(size_t)n * HH + k] = (_Float16)W_emb[e];
      }
    } else if (q < 138) {                // W1^T  (W1T[n*FIN+k] = W1[k*HH+n])
      for (int e = (q - 136) * 256 + threadIdx.x; e < HH * FIN; e += 512) {
        const int n = e >> 7, k = e & 127;
        W1T[e] = (_Float16)W1[(size_t)k * HH + n];
      }
    } else {                             // y0/y1 <- head biases
      const float v0 = bt0[0], v1 = bt1[0];
      for (int i = (q - 138) * 256 + threadIdx.x; i < 2 * NN; i += 2048)
        dout[i] = (i < NN) ? v0 : v1;
    }
    return;
  }

  const f32x4* Ar = c4(A + (size_t)row * NN);
  __shared__ int   s_cnt;
  __shared__ float s_rs[4];
  if (threadIdx.x == 0) s_cnt = 0;
  __syncthreads();

  float rs = 0.f;
  int* myCols = cols + (size_t)row * CAP;
  #pragma unroll
  for (int it = 0; it < NN / 4 / 256; ++it) {
    const int idx = it * 256 + threadIdx.x;
    const f32x4 a = __builtin_nontemporal_load(Ar + idx);
    const int base = idx * 4;
    #pragma unroll
    for (int u = 0; u < 4; ++u) {
      if (a[u] != 0.0f) {
        rs += a[u];
        int p = atomicAdd(&s_cnt, 1);
        if (p < CAP) myCols[p] = base + u;
      }
    }
  }
  #pragma unroll
  for (int off = 32; off > 0; off >>= 1) rs += __shfl_down(rs, off);
  const int wid = threadIdx.x >> 6;
  if ((threadIdx.x & 63) == 0) s_rs[wid] = rs;
  __syncthreads();
  if (threadIdx.x == 0) {
    const float R = s_rs[0] + s_rs[1] + s_rs[2] + s_rs[3];
    int n = s_cnt; if (n > CAP) n = CAP;
    cnt[row]  = n;
    dinv[row] = rsqrtf(R + 1.0f);
    expo[row] = treat[row] * R / (R + 1e-8f);
  }
}

// ---------------------------------------------------------------------------
// agg0: aggX = dinv[i]*(sum_j dinv[j]*Xh[j,:] + dinv[i]*Xh[i,:]) -> fp16
// Wave per node.  Row = 128 f16 = 256 B: lanes 0..31 handle even neighbors,
// lanes 32..63 odd neighbors, f16x4 (8 B)/lane -> half the VMEM instructions;
// shfl_xor(32) combine.  fp32 accumulate.
// ---------------------------------------------------------------------------
__global__ __launch_bounds__(256) void k_agg0h(
    const _Float16* __restrict__ Xh,
    const int* __restrict__ cols, const int* __restrict__ cnt,
    const float* __restrict__ dinv, _Float16* __restrict__ out)
{
  const int wid  = threadIdx.x >> 6;
  const int lane = threadIdx.x & 63;
  const int half = lane >> 5;          // 0: even neighbors, 1: odd
  const int cl   = lane & 31;          // col group: cols 4*cl..4*cl+3
  const int i    = blockIdx.x * 4 + wid;
  __shared__ int   s_cols[4][CAP];
  __shared__ float s_w[4][CAP];

  const int n = cnt[i];
  if (lane < n) {
    const int j = cols[(size_t)i * CAP + lane];
    s_cols[wid][lane] = j;  s_w[wid][lane] = dinv[j];
  }
  if (lane + 64 < n) {
    const int j = cols[(size_t)i * CAP + lane + 64];
    s_cols[wid][lane + 64] = j;  s_w[wid][lane + 64] = dinv[j];
  }
  __syncthreads();

  const float di = dinv[i];
  f32x4 acc = {0.f, 0.f, 0.f, 0.f};
  if (half == 0) {                      // self-loop term once
    const f16x4 sv = *(const f16x4*)&Xh[(size_t)i * FIN + 4 * cl];
    #pragma unroll
    for (int q = 0; q < 4; ++q) acc[q] = di * (float)sv[q];
  }
  for (int t = half; t < n; t += 2) {
    const int   j = s_cols[wid][t];
    const float w = s_w[wid][t];
    const f16x4 v = *(const f16x4*)&Xh[(size_t)j * FIN + 4 * cl];
    #pragma unroll
    for (int q = 0; q < 4; ++q) acc[q] += w * (float)v[q];
  }
  #pragma unroll
  for (int q = 0; q < 4; ++q) acc[q] += __shfl_xor(acc[q], 32);
  if (half == 0) {
    f16x4 oh;
    #pragma unroll
    for (int q = 0; q < 4; ++q) oh[q] = (_Float16)(di * acc[q]);
    *(f16x4*)&out[(size_t)i * FIN + 4 * cl] = oh;
  }
}

// ---------------------------------------------------------------------------
// aggh: h2 = relu(dinv[i]*(sum dinv[j]*M[j,:] + dinv[i]*M[i,:]) + b) -> fp16
// Row = 256 f16 = 512 B: even/odd neighbor split, f16x8 (16 B)/lane.
// ---------------------------------------------------------------------------
__global__ __launch_bounds__(256) void k_aggh(
    const _Float16* __restrict__ M,
    const int* __restrict__ cols, const int* __restrict__ cnt,
    const float* __restrict__ dinv, const float* __restrict__ bias,
    _Float16* __restrict__ out)
{
  const int wid  = threadIdx.x >> 6;
  const int lane = threadIdx.x & 63;
  const int half = lane >> 5;
  const int cl   = lane & 31;          // cols 8*cl..8*cl+7
  const int i    = blockIdx.x * 4 + wid;
  __shared__ int   s_cols[4][CAP];
  __shared__ float s_w[4][CAP];

  const int n = cnt[i];
  if (lane < n) {
    const int j = cols[(size_t)i * CAP + lane];
    s_cols[wid][lane] = j;  s_w[wid][lane] = dinv[j];
  }
  if (lane + 64 < n) {
    const int j = cols[(size_t)i * CAP + lane + 64];
    s_cols[wid][lane + 64] = j;  s_w[wid][lane + 64] = dinv[j];
  }
  __syncthreads();

  const float di = dinv[i];
  float acc[8] = {};
  if (half == 0) {
    const f16x8 sv = *(const f16x8*)&M[(size_t)i * HH + 8 * cl];
    #pragma unroll
    for (int q = 0; q < 8; ++q) acc[q] = di * (float)sv[q];
  }
  for (int t = half; t < n; t += 2) {
    const int   j = s_cols[wid][t];
    const float w = s_w[wid][t];
    const f16x8 v = *(const f16x8*)&M[(size_t)j * HH + 8 * cl];
    #pragma unroll
    for (int q = 0; q < 8; ++q) acc[q] += w * (float)v[q];
  }
  #pragma unroll
  for (int q = 0; q < 8; ++q) acc[q] += __shfl_xor(acc[q], 32);
  if (half == 0) {
    const f32x4 b0 = *c4(&bias[8 * cl]);
    const f32x4 b1 = *c4(&bias[8 * cl + 4]);
    f16x8 oh;
    #pragma unroll
    for (int q = 0; q < 4; ++q) {
      oh[q]     = (_Float16)fmaxf(di * acc[q]     + b0[q], 0.f);
      oh[q + 4] = (_Float16)fmaxf(di * acc[q + 4] + b1[q], 0.f);
    }
    *(f16x8*)&out[(size_t)i * HH + 8 * cl] = oh;
  }
}

// ---------------------------------------------------------------------------
// MFMA fp16 GEMM: out[8192 x 256] = Ah[8192 x K] @ B, B given TRANSPOSED
// fp16 (BT[n][k]).  Block = 4 waves, 64 rows x 64 cols; wave = 16 rows.
// Frag layout (HW-verified m89): A row=lane&15, k=(lane>>4)*8+i;
// B col=lane&15, same k; D col=lane&15, row=(lane>>4)*4+reg.
// MODE 0: raw fp16 out.  MODE 1: relu(acc+bias) fp16 out.
// MODE 2: +expo*ebrow+bias, relu, fp32 out + fused y0/y1 head dots.
// ---------------------------------------------------------------------------
template<int K, int MODE>
__global__ __launch_bounds__(256) void k_gemm_mfma(
    const _Float16* __restrict__ Ah, const _Float16* __restrict__ BT,
    const float* __restrict__ Wfull,   // fp32 W_emb (exposure row) [MODE 2]
    const float* __restrict__ bias, const float* __restrict__ expo,
    const float* __restrict__ Wt0, const float* __restrict__ Wt1,
    float* __restrict__ out, _Float16* __restrict__ out16,
    float* __restrict__ y0, float* __restrict__ y1)
{
  const int tid = threadIdx.x;
  const int w = tid >> 6, l = tid & 63;
  const int r0 = (blockIdx.x & 127) * 64 + w * 16;   // wave's 16 rows
  const int c0 = (blockIdx.x >> 7) * 64;             // block's 64 cols
  const int lr = l & 15;                             // frag row/col index
  const int lk = (l >> 4) * 8;                       // frag k offset

  f32x4 acc[4] = {{0.f,0.f,0.f,0.f},{0.f,0.f,0.f,0.f},
                  {0.f,0.f,0.f,0.f},{0.f,0.f,0.f,0.f}};
  const _Float16* Aptr = Ah + (size_t)(r0 + lr) * K + lk;
  const _Float16* Bptr = BT + (size_t)(c0 + lr) * K + lk;

  #pragma unroll
  for (int k0 = 0; k0 < K; k0 += 32) {
    const f16x8 a = *(const f16x8*)(Aptr + k0);
    #pragma unroll
    for (int nt = 0; nt < 4; ++nt) {
      const f16x8 b = *(const f16x8*)(Bptr + (size_t)nt * 16 * K + k0);
      acc[nt] = __builtin_amdgcn_mfma_f32_16x16x32_f16(a, b, acc[nt], 0, 0, 0);
    }
  }

  const int rbase = r0 + (l >> 4) * 4;   // this quarter-wave's 4 output rows
  if constexpr (MODE == 0) {
    #pragma unroll
    for (int r = 0; r < 4; ++r)
      #pragma unroll
      for (int nt = 0; nt < 4; ++nt)
        out16[(size_t)(rbase + r) * HH + c0 + 16 * nt + lr] = (_Float16)acc[nt][r];
  } else if constexpr (MODE == 1) {
    float bs[4];
    #pragma unroll
    for (int nt = 0; nt < 4; ++nt) bs[nt] = bias[c0 + 16 * nt + lr];
    #pragma unroll
    for (int r = 0; r < 4; ++r)
      #pragma unroll
      for (int nt = 0; nt < 4; ++nt)
        out16[(size_t)(rbase + r) * HH + c0 + 16 * nt + lr] =
            (_Float16)fmaxf(acc[nt][r] + bs[nt], 0.f);
  } else {
    float eb[4], bs[4], w0[4], w1[4];
    #pragma unroll
    for (int nt = 0; nt < 4; ++nt) {
      const int c = c0 + 16 * nt + lr;
      eb[nt] = Wfull[(size_t)HH * HH + c];   // exposure row of W_emb (fp32)
      bs[nt] = bias[c];
      w0[nt] = Wt0[c];
      w1[nt] = Wt1[c];
    }
    #pragma unroll
    for (int r = 0; r < 4; ++r) {
      const int R = rbase + r;
      const float e = expo[R];
      float s0 = 0.f, s1 = 0.f;
      #pragma unroll
      for (int nt = 0; nt < 4; ++nt) {
        float v = fmaxf(acc[nt][r] + e * eb[nt] + bs[nt], 0.f);
        out[(size_t)R * HH + c0 + 16 * nt + lr] = v;
        s0 += v * w0[nt];
        s1 += v * w1[nt];
      }
      #pragma unroll
      for (int off = 8; off > 0; off >>= 1) {   // reduce 16-lane quarter-wave
        s0 += __shfl_down(s0, off);
        s1 += __shfl_down(s1, off);
      }
      if (lr == 0) {
        atomicAdd(&y0[R], s0);
        atomicAdd(&y1[R], s1);
      }
    }
  }
}

// ---------------------------------------------------------------------------
extern "C" void kernel_launch(void* const* d_in, const int* in_sizes, int n_in,
                              void* d_out, int out_size, void* d_ws, size_t ws_size,
                              hipStream_t stream)
{
  const float* A      = (const float*)d_in[0];
  const float* feats  = (const float*)d_in[1];
  const float* treat  = (const float*)d_in[2];
  const float* W1     = (const float*)d_in[3];
  const float* b1     = (const float*)d_in[4];
  const float* W2     = (const float*)d_in[5];
  const float* b2     = (const float*)d_in[6];
  const float* W_emb  = (const float*)d_in[7];
  const float* b_emb  = (const float*)d_in[8];
  const float* W_t0   = (const float*)d_in[9];
  const float* b_t0   = (const float*)d_in[10];
  const float* W_t1   = (const float*)d_in[11];
  const float* b_t1   = (const float*)d_in[12];
  float* dout = (float*)d_out;

  // workspace layout (~20.5 MiB, all 16B-aligned)
  int*      cols  = (int*)d_ws;                      // NN*CAP ints (4 MiB)
  int*      cnt   = cols + (size_t)NN * CAP;         // NN
  float*    dinv  = (float*)(cnt + NN);              // NN
  float*    expo  = dinv + NN;                       // NN
  _Float16* Xh    = (_Float16*)(expo + NN);          // NN*FIN f16 (2 MiB)
  _Float16* aggXh = Xh + (size_t)NN * FIN;           // NN*FIN f16 (2 MiB)
  _Float16* h1h   = aggXh + (size_t)NN * FIN;        // NN*HH f16 (4 MiB)
  _Float16* h1w2h = h1h + (size_t)NN * HH;           // NN*HH f16 (4 MiB)
  _Float16* h2h   = h1w2h + (size_t)NN * HH;         // NN*HH f16 (4 MiB)
  _Float16* W1T   = h2h + (size_t)NN * HH;           // HH*FIN f16 (64 KiB)
  _Float16* W2T   = W1T + (size_t)HH * FIN;          // HH*HH f16 (128 KiB)
  _Float16* WembT = W2T + (size_t)HH * HH;           // HH*HH f16 (128 KiB)

  float* y0  = dout;
  float* y1  = dout + NN;
  float* emb = dout + 2 * NN;

  // 1. A scan + fp16 conversions (X, W1^T, W2^T, W_emb^T) + y-bias init
  k_build<<<NN + 146, 256, 0, stream>>>(A, treat, feats, W1, W2, W_emb,
                                        b_t0, b_t1,
                                        cols, cnt, dinv, expo,
                                        Xh, W1T, W2T, WembT, dout);
  // 2. aggX = nA @ X -> fp16   (even/odd-split gather)
  k_agg0h<<<NN / 4, 256, 0, stream>>>(Xh, cols, cnt, dinv, aggXh);
  // 3. h1 = relu(aggX @ W1 + b1) -> fp16   (MFMA)
  k_gemm_mfma<FIN, 1><<<512, 256, 0, stream>>>(
      aggXh, W1T, nullptr, b1, nullptr, nullptr, nullptr,
      nullptr, h1h, nullptr, nullptr);
  // 4. h1W2 = h1 @ W2 -> fp16              (MFMA)
  k_gemm_mfma<HH, 0><<<512, 256, 0, stream>>>(
      h1h, W2T, nullptr, nullptr, nullptr, nullptr, nullptr,
      nullptr, h1w2h, nullptr, nullptr);
  // 5. h2 = relu(nA @ h1W2 + b2) -> fp16   (even/odd-split gather)
  k_aggh<<<NN / 4, 256, 0, stream>>>(h1w2h, cols, cnt, dinv, b2, h2h);
  // 6. emb = relu(h2 @ W_emb + expo*ebrow + b_emb) + heads  (MFMA)
  k_gemm_mfma<HH, 2><<<512, 256, 0, stream>>>(
      h2h, WembT, W_emb, b_emb, expo, W_t0, W_t1,
      emb, nullptr, y0, y1);
}